// Round 1
// baseline (1889.744 us; speedup 1.0000x reference)
//
#include <hip/hip_runtime.h>
#include <hip/hip_bf16.h>
#include <math.h>

// Problem constants (from reference)
#define Bq   4
#define Tq   512
#define Hq   512
#define Vq   32000
#define Sq   512
#define SDVq 300
#define TDVq 512
#define ROWS (Bq * Tq)            // 2048
#define OUTW (Vq + SDVq + TDVq)   // 32812

// -------------------------------------------------------------------------
// K1: p = softmax(h @ Wp + bp) per row; one wave per row.
__global__ void compute_p(const float* __restrict__ hiddens,
                          const float* __restrict__ Wp,
                          const float* __restrict__ bp,
                          float* __restrict__ p) {
    int row  = blockIdx.x;
    int lane = threadIdx.x;   // 64 lanes
    const float* h = hiddens + (size_t)row * Hq;
    float a0 = 0.f, a1 = 0.f, a2 = 0.f;
    for (int i = lane; i < Hq; i += 64) {
        float hv = h[i];
        a0 += hv * Wp[i * 3 + 0];
        a1 += hv * Wp[i * 3 + 1];
        a2 += hv * Wp[i * 3 + 2];
    }
    for (int off = 32; off > 0; off >>= 1) {
        a0 += __shfl_down(a0, off);
        a1 += __shfl_down(a1, off);
        a2 += __shfl_down(a2, off);
    }
    if (lane == 0) {
        float l0 = a0 + bp[0], l1 = a1 + bp[1], l2 = a2 + bp[2];
        float M  = fmaxf(l0, fmaxf(l1, l2));
        float e0 = expf(l0 - M), e1 = expf(l1 - M), e2 = expf(l2 - M);
        float inv = 1.f / (e0 + e1 + e2);
        p[row * 3 + 0] = e0 * inv;
        p[row * 3 + 1] = e1 * inv;
        p[row * 3 + 2] = e2 * inv;
    }
}

// -------------------------------------------------------------------------
// K2: extract one-hot index per map row (argmax). One wave per row.
__global__ void extract_idx(const float* __restrict__ map, int ncols,
                            int* __restrict__ idx) {
    int row  = blockIdx.x;
    int lane = threadIdx.x;
    const float* r = map + (size_t)row * ncols;
    float best = -1.f; int bi = 0;
    for (int i = lane; i < ncols; i += 64) {
        float v = r[i];
        if (v > best) { best = v; bi = i; }
    }
    for (int off = 32; off > 0; off >>= 1) {
        float ob  = __shfl_down(best, off);
        int   obi = __shfl_down(bi, off);
        if (ob > best) { best = ob; bi = obi; }
    }
    if (lane == 0) idx[row] = bi;
}

// -------------------------------------------------------------------------
// K3: scores = hf @ Wv + bv written into out[:, 0:32000] (stride OUTW).
// col 0 forced to -1e30 (acts as -inf for the softmax).
// Classic fp32 LDS-tiled GEMM: 64x64 tile, BK=16, 256 threads, 4x4/thread.
#define BM 64
#define BN 64
#define BK 16
__global__ __launch_bounds__(256)
void gemm_scores(const float* __restrict__ A,   // hiddens (2048 x 512)
                 const float* __restrict__ Bm,  // Wv (512 x 32000)
                 const float* __restrict__ bv,
                 float* __restrict__ out) {
    __shared__ float As[BK][BM + 1];
    __shared__ float Bs[BK][BN + 1];
    int bm = blockIdx.y * BM;
    int bn = blockIdx.x * BN;
    int tid = threadIdx.x;
    int tx = tid % 16;   // col group
    int ty = tid / 16;   // row group
    float acc[4][4] = {};

    for (int k0 = 0; k0 < Hq; k0 += BK) {
        for (int i = tid; i < BM * BK; i += 256) {
            int r = i / BK, c = i % BK;
            As[c][r] = A[(size_t)(bm + r) * Hq + k0 + c];
        }
        for (int i = tid; i < BK * BN; i += 256) {
            int r = i / BN, c = i % BN;
            Bs[r][c] = Bm[(size_t)(k0 + r) * Vq + bn + c];
        }
        __syncthreads();
#pragma unroll
        for (int k = 0; k < BK; ++k) {
            float a[4], b[4];
#pragma unroll
            for (int i = 0; i < 4; ++i) a[i] = As[k][ty * 4 + i];
#pragma unroll
            for (int j = 0; j < 4; ++j) b[j] = Bs[k][tx * 4 + j];
#pragma unroll
            for (int i = 0; i < 4; ++i)
#pragma unroll
                for (int j = 0; j < 4; ++j) acc[i][j] += a[i] * b[j];
        }
        __syncthreads();
    }
#pragma unroll
    for (int i = 0; i < 4; ++i) {
        int m = bm + ty * 4 + i;
#pragma unroll
        for (int j = 0; j < 4; ++j) {
            int n = bn + tx * 4 + j;
            float v = acc[i][j] + bv[n];
            if (n == 0) v = -1e30f;
            out[(size_t)m * OUTW + n] = v;
        }
    }
}

// -------------------------------------------------------------------------
// K4: in-place row softmax over cols [0,32000), scaled by p_generate.
__global__ __launch_bounds__(256)
void softmax_rows(float* __restrict__ out, const float* __restrict__ p) {
    int row = blockIdx.x;
    int tid = threadIdx.x;
    float* rp = out + (size_t)row * OUTW;
    float pgen = p[row * 3 + 2];

    float m = -INFINITY, l = 0.f;
    for (int i = tid; i < Vq; i += 256) {
        float v = rp[i];
        if (v > m) { l = l * expf(m - v) + 1.f; m = v; }
        else       { l += expf(v - m); }
    }
    __shared__ float ms[256], ls[256];
    ms[tid] = m; ls[tid] = l;
    __syncthreads();
    for (int s = 128; s > 0; s >>= 1) {
        if (tid < s) {
            float m1 = ms[tid], l1 = ls[tid];
            float m2 = ms[tid + s], l2 = ls[tid + s];
            float M = fmaxf(m1, m2);
            ls[tid] = l1 * expf(m1 - M) + l2 * expf(m2 - M);
            ms[tid] = M;
        }
        __syncthreads();
    }
    float M = ms[0], L = ls[0];
    float scale = pgen / L;
    for (int i = tid; i < Vq; i += 256) {
        rp[i] = expf(rp[i] - M) * scale;
    }
}

// -------------------------------------------------------------------------
// K5: scatter-add copy distribution: out[row, out_off+v] =
//       p[row,pcol] * sum_{s: idx[b,s]==v} att[row,s]
__global__ __launch_bounds__(256)
void copy_scatter(const float* __restrict__ att, const int* __restrict__ idx,
                  const float* __restrict__ p, int pcol, int natt, int nout,
                  float* __restrict__ out, int out_off) {
    int row = blockIdx.x;       // b*T + t
    int b   = row >> 9;         // /512
    int tid = threadIdx.x;
    __shared__ float acc[TDVq]; // max(nout)
    for (int i = tid; i < nout; i += 256) acc[i] = 0.f;
    __syncthreads();
    const float* arow = att + (size_t)row * natt;
    const int*   ib   = idx + b * natt;
    for (int s = tid; s < natt; s += 256) {
        atomicAdd(&acc[ib[s]], arow[s]);
    }
    __syncthreads();
    float pc = p[row * 3 + pcol];
    float* orow = out + (size_t)row * OUTW + out_off;
    for (int v = tid; v < nout; v += 256) orow[v] = acc[v] * pc;
}

// -------------------------------------------------------------------------
// K6: argmax over full 32812-wide row -> predictions (stored as float).
__global__ __launch_bounds__(256)
void argmax_rows(const float* __restrict__ out, float* __restrict__ pred) {
    int row = blockIdx.x;
    int tid = threadIdx.x;
    const float* rp = out + (size_t)row * OUTW;
    float best = -INFINITY; int bi = 0x7fffffff;
    for (int i = tid; i < OUTW; i += 256) {
        float v = rp[i];
        if (v > best) { best = v; bi = i; }   // strided ascending -> first max kept
    }
    __shared__ float bs[256];
    __shared__ int   is_[256];
    bs[tid] = best; is_[tid] = bi;
    __syncthreads();
    for (int s = 128; s > 0; s >>= 1) {
        if (tid < s) {
            float v2 = bs[tid + s]; int i2 = is_[tid + s];
            if (v2 > bs[tid] || (v2 == bs[tid] && i2 < is_[tid])) {
                bs[tid] = v2; is_[tid] = i2;
            }
        }
        __syncthreads();
    }
    if (tid == 0) pred[row] = (float)is_[0];
}

// -------------------------------------------------------------------------
extern "C" void kernel_launch(void* const* d_in, const int* in_sizes, int n_in,
                              void* d_out, int out_size, void* d_ws, size_t ws_size,
                              hipStream_t stream) {
    const float* hiddens = (const float*)d_in[0];
    const float* Wp      = (const float*)d_in[1];
    const float* bp      = (const float*)d_in[2];
    const float* Wv      = (const float*)d_in[3];
    const float* bv      = (const float*)d_in[4];
    const float* src_att = (const float*)d_in[5];
    const float* src_map = (const float*)d_in[6];
    const float* tgt_att = (const float*)d_in[7];
    const float* tgt_map = (const float*)d_in[8];

    float* out  = (float*)d_out;
    float* pred = out + (size_t)ROWS * OUTW;

    // workspace layout
    float* p_ws    = (float*)d_ws;                    // 2048*3 floats
    int*   sidx_ws = (int*)((char*)d_ws + 24576);     // 2048 ints
    int*   tidx_ws = (int*)((char*)d_ws + 24576 + 8192); // 2048 ints

    // K1: gate probabilities
    compute_p<<<ROWS, 64, 0, stream>>>(hiddens, Wp, bp, p_ws);

    // K2: one-hot index extraction
    extract_idx<<<Bq * Sq, 64, 0, stream>>>(src_map, SDVq, sidx_ws);
    extract_idx<<<Bq * Tq, 64, 0, stream>>>(tgt_map, TDVq, tidx_ws);

    // K3: scores GEMM into vocab region of out
    dim3 ggrid(Vq / BN, ROWS / BM);   // (500, 32)
    gemm_scores<<<ggrid, 256, 0, stream>>>(hiddens, Wv, bv, out);

    // K4: in-place softmax * p_generate
    softmax_rows<<<ROWS, 256, 0, stream>>>(out, p_ws);

    // K5: copy distributions
    copy_scatter<<<ROWS, 256, 0, stream>>>(src_att, sidx_ws, p_ws, 0, Sq, SDVq,
                                           out, Vq);
    copy_scatter<<<ROWS, 256, 0, stream>>>(tgt_att, tidx_ws, p_ws, 1, TDVq, TDVq,
                                           out, Vq + SDVq);

    // K6: predictions
    argmax_rows<<<ROWS, 256, 0, stream>>>(out, pred);
}

// Round 2
// 656.916 us; speedup vs baseline: 2.8767x; 2.8767x over previous
//
#include <hip/hip_runtime.h>
#include <hip/hip_bf16.h>
#include <math.h>

// Problem constants (from reference)
#define Bq   4
#define Tq   512
#define Hq   512
#define Vq   32000
#define Sq   512
#define SDVq 300
#define TDVq 512
#define ROWS (Bq * Tq)            // 2048
#define OUTW (Vq + SDVq + TDVq)   // 32812

typedef __bf16 bf16x8 __attribute__((ext_vector_type(8)));
typedef float  fx4    __attribute__((ext_vector_type(4)));

__device__ __forceinline__ void async16(const void* g, void* l) {
    __builtin_amdgcn_global_load_lds(
        (const __attribute__((address_space(1))) void*)g,
        (__attribute__((address_space(3))) void*)l, 16, 0, 0);
}

// -------------------------------------------------------------------------
// K1: p = softmax(h @ Wp + bp) per row; one wave per row.
__global__ void compute_p(const float* __restrict__ hiddens,
                          const float* __restrict__ Wp,
                          const float* __restrict__ bp,
                          float* __restrict__ p) {
    int row  = blockIdx.x;
    int lane = threadIdx.x;   // 64 lanes
    const float* h = hiddens + (size_t)row * Hq;
    float a0 = 0.f, a1 = 0.f, a2 = 0.f;
    for (int i = lane; i < Hq; i += 64) {
        float hv = h[i];
        a0 += hv * Wp[i * 3 + 0];
        a1 += hv * Wp[i * 3 + 1];
        a2 += hv * Wp[i * 3 + 2];
    }
    for (int off = 32; off > 0; off >>= 1) {
        a0 += __shfl_down(a0, off);
        a1 += __shfl_down(a1, off);
        a2 += __shfl_down(a2, off);
    }
    if (lane == 0) {
        float l0 = a0 + bp[0], l1 = a1 + bp[1], l2 = a2 + bp[2];
        float M  = fmaxf(l0, fmaxf(l1, l2));
        float e0 = expf(l0 - M), e1 = expf(l1 - M), e2 = expf(l2 - M);
        float inv = 1.f / (e0 + e1 + e2);
        p[row * 3 + 0] = e0 * inv;
        p[row * 3 + 1] = e1 * inv;
        p[row * 3 + 2] = e2 * inv;
    }
}

// -------------------------------------------------------------------------
// K2: extract one-hot index per map row (argmax). One wave per row.
__global__ void extract_idx(const float* __restrict__ map, int ncols,
                            int* __restrict__ idx) {
    int row  = blockIdx.x;
    int lane = threadIdx.x;
    const float* r = map + (size_t)row * ncols;
    float best = -1.f; int bi = 0;
    for (int i = lane; i < ncols; i += 64) {
        float v = r[i];
        if (v > best) { best = v; bi = i; }
    }
    for (int off = 32; off > 0; off >>= 1) {
        float ob  = __shfl_down(best, off);
        int   obi = __shfl_down(bi, off);
        if (ob > best) { best = ob; bi = obi; }
    }
    if (lane == 0) idx[row] = bi;
}

// -------------------------------------------------------------------------
// Conversion: hiddens fp32 -> bf16 (same layout, k contiguous)
__global__ __launch_bounds__(256)
void convert_a(const float* __restrict__ in, __hip_bfloat16* __restrict__ o) {
    int i = blockIdx.x * 256 + threadIdx.x;
    float4 v = ((const float4*)in)[i];
    __hip_bfloat16* op = o + (size_t)i * 4;
    op[0] = __float2bfloat16(v.x);
    op[1] = __float2bfloat16(v.y);
    op[2] = __float2bfloat16(v.z);
    op[3] = __float2bfloat16(v.w);
}

// Transpose+convert: Wv (512 x 32000 fp32) -> Wt (32000 x 512 bf16)
__global__ __launch_bounds__(256)
void transpose_wv(const float* __restrict__ Wv, __hip_bfloat16* __restrict__ Wt) {
    __shared__ float t[32][33];
    int n0 = blockIdx.x * 32, k0 = blockIdx.y * 32;
    int tx = threadIdx.x, ty = threadIdx.y;   // 32 x 8
#pragma unroll
    for (int r = 0; r < 4; ++r)
        t[ty + r * 8][tx] = Wv[(size_t)(k0 + ty + r * 8) * Vq + n0 + tx];
    __syncthreads();
#pragma unroll
    for (int r = 0; r < 4; ++r)
        Wt[(size_t)(n0 + ty + r * 8) * Hq + k0 + tx] =
            __float2bfloat16(t[tx][ty + r * 8]);
}

// -------------------------------------------------------------------------
// K3: bf16 MFMA GEMM (m97 structure). C = A(2048x512) * Wt^T(512x32000) + bv,
// written to out[:, 0:32000] (stride OUTW), col 0 forced to -1e30.
// 128x128 block tile, BK=32, 4 waves each computing 64x64 via 4x4 MFMA 16x16x32.
// LDS layout: [kchunk(4)][row(128)][8 bf16] -> fragment ds_read_b128 contiguous.
__global__ __launch_bounds__(256)
void gemm_mfma(const __hip_bfloat16* __restrict__ A,
               const __hip_bfloat16* __restrict__ Bt,
               const float* __restrict__ bv,
               float* __restrict__ out) {
    __shared__ __align__(16) unsigned short As[4096];   // 8 KB
    __shared__ __align__(16) unsigned short Bs[4096];   // 8 KB
    int tid  = threadIdx.x;
    int wave = tid >> 6, lane = tid & 63;
    int bm = blockIdx.x * 128;   // 16 m-blocks
    int bn = blockIdx.y * 128;   // 250 n-blocks
    int wr = wave >> 1, wc = wave & 1;
    int lr = lane & 15;          // fragment row/col within 16
    int kq = lane >> 4;          // k-quad (0..3)

    fx4 acc[4][4];
#pragma unroll
    for (int i = 0; i < 4; ++i)
#pragma unroll
        for (int j = 0; j < 4; ++j)
            acc[i][j] = (fx4){0.f, 0.f, 0.f, 0.f};

    // staging chunk ids: chunk c covers row=c&127, kchunk=c>>7 (16B each)
    int c0 = tid, c1 = tid + 256;
    int ar0 = c0 & 127, ak0 = (c0 >> 7) * 8;
    int ar1 = c1 & 127, ak1 = (c1 >> 7) * 8;
    const unsigned short* Ag = (const unsigned short*)A;
    const unsigned short* Bg = (const unsigned short*)Bt;
    unsigned short* As0 = &As[(wave << 6) * 8];
    unsigned short* As1 = &As[(256 + (wave << 6)) * 8];
    unsigned short* Bs0 = &Bs[(wave << 6) * 8];
    unsigned short* Bs1 = &Bs[(256 + (wave << 6)) * 8];

    for (int k0 = 0; k0 < Hq; k0 += 32) {
        async16(Ag + (size_t)(bm + ar0) * Hq + k0 + ak0, As0);
        async16(Ag + (size_t)(bm + ar1) * Hq + k0 + ak1, As1);
        async16(Bg + (size_t)(bn + ar0) * Hq + k0 + ak0, Bs0);
        async16(Bg + (size_t)(bn + ar1) * Hq + k0 + ak1, Bs1);
        __syncthreads();

        bf16x8 af[4], bfr[4];
#pragma unroll
        for (int i = 0; i < 4; ++i) {
            int row = wr * 64 + i * 16 + lr;
            af[i] = *(const bf16x8*)&As[(size_t)(kq * 128 + row) * 8];
        }
#pragma unroll
        for (int j = 0; j < 4; ++j) {
            int col = wc * 64 + j * 16 + lr;
            bfr[j] = *(const bf16x8*)&Bs[(size_t)(kq * 128 + col) * 8];
        }
#pragma unroll
        for (int i = 0; i < 4; ++i)
#pragma unroll
            for (int j = 0; j < 4; ++j)
                acc[i][j] = __builtin_amdgcn_mfma_f32_16x16x32_bf16(
                    af[i], bfr[j], acc[i][j], 0, 0, 0);
        __syncthreads();
    }

    // epilogue: C/D layout col=lane&15, row=(lane>>4)*4+reg
    float bvv[4];
#pragma unroll
    for (int j = 0; j < 4; ++j)
        bvv[j] = bv[bn + wc * 64 + j * 16 + lr];
#pragma unroll
    for (int i = 0; i < 4; ++i) {
        int gr0 = bm + wr * 64 + i * 16 + kq * 4;
#pragma unroll
        for (int j = 0; j < 4; ++j) {
            int gc = bn + wc * 64 + j * 16 + lr;
#pragma unroll
            for (int r = 0; r < 4; ++r) {
                float v = acc[i][j][r] + bvv[j];
                if (gc == 0) v = -1e30f;
                out[(size_t)(gr0 + r) * OUTW + gc] = v;
            }
        }
    }
}

// -------------------------------------------------------------------------
// K4: in-place row softmax over cols [0,32000), scaled by p_generate.
// Fused vocab argmax (monotone transform) -> candidate slot 0.
__global__ __launch_bounds__(256)
void softmax_rows(float* __restrict__ out, const float* __restrict__ p,
                  float* __restrict__ cval, int* __restrict__ cidx) {
    int row = blockIdx.x;
    int tid = threadIdx.x;
    float* rp = out + (size_t)row * OUTW;
    const float4* rv = (const float4*)rp;

    float m = -INFINITY, l = 0.f; int mi = 0;
    for (int i = tid; i < Vq / 4; i += 256) {
        float4 v = rv[i];
        float vv[4] = {v.x, v.y, v.z, v.w};
#pragma unroll
        for (int c = 0; c < 4; ++c) {
            float x = vv[c];
            if (x > m) { l = l * __expf(m - x) + 1.f; m = x; mi = i * 4 + c; }
            else       { l += __expf(x - m); }
        }
    }
    __shared__ float sm[256], sl[256];
    __shared__ int   si[256];
    sm[tid] = m; sl[tid] = l; si[tid] = mi;
    __syncthreads();
    for (int s = 128; s > 0; s >>= 1) {
        if (tid < s) {
            float m1 = sm[tid], l1 = sl[tid]; int i1 = si[tid];
            float m2 = sm[tid + s], l2 = sl[tid + s]; int i2 = si[tid + s];
            float M = fmaxf(m1, m2);
            sl[tid] = l1 * __expf(m1 - M) + l2 * __expf(m2 - M);
            sm[tid] = M;
            si[tid] = (m2 > m1 || (m2 == m1 && i2 < i1)) ? i2 : i1;
        }
        __syncthreads();
    }
    float M = sm[0], L = sl[0];
    float pgen = p[row * 3 + 2];
    float scale = pgen / L;
    if (tid == 0) { cval[row * 3] = scale; cidx[row * 3] = si[0]; }

    float4* wv4 = (float4*)rp;
    for (int i = tid; i < Vq / 4; i += 256) {
        float4 v = rv[i];
        v.x = __expf(v.x - M) * scale;
        v.y = __expf(v.y - M) * scale;
        v.z = __expf(v.z - M) * scale;
        v.w = __expf(v.w - M) * scale;
        wv4[i] = v;
    }
}

// -------------------------------------------------------------------------
// K5: scatter-add copy distribution + fused region argmax -> candidate slot.
__global__ __launch_bounds__(256)
void copy_scatter(const float* __restrict__ att, const int* __restrict__ idx,
                  const float* __restrict__ p, int pcol, int slot,
                  int natt, int nout, float* __restrict__ out, int out_off,
                  float* __restrict__ cval, int* __restrict__ cidx) {
    int row = blockIdx.x;       // b*T + t
    int b   = row >> 9;         // /512
    int tid = threadIdx.x;
    __shared__ float acc[TDVq];
    for (int i = tid; i < nout; i += 256) acc[i] = 0.f;
    __syncthreads();
    const float* arow = att + (size_t)row * natt;
    const int*   ib   = idx + b * natt;
    for (int s = tid; s < natt; s += 256) {
        atomicAdd(&acc[ib[s]], arow[s]);
    }
    __syncthreads();
    float pc = p[row * 3 + pcol];
    float* orow = out + (size_t)row * OUTW + out_off;
    float bm_ = -INFINITY; int bi = 0;
    for (int v = tid; v < nout; v += 256) {
        float val = acc[v] * pc;
        orow[v] = val;
        if (val > bm_) { bm_ = val; bi = v; }
    }
    __shared__ float bs[256];
    __shared__ int   is_[256];
    bs[tid] = bm_; is_[tid] = bi;
    __syncthreads();
    for (int s = 128; s > 0; s >>= 1) {
        if (tid < s) {
            float v2 = bs[tid + s]; int i2 = is_[tid + s];
            if (v2 > bs[tid] || (v2 == bs[tid] && i2 < is_[tid])) {
                bs[tid] = v2; is_[tid] = i2;
            }
        }
        __syncthreads();
    }
    if (tid == 0) { cval[row * 3 + slot] = bs[0]; cidx[row * 3 + slot] = out_off + is_[0]; }
}

// -------------------------------------------------------------------------
// K6: combine 3 per-region argmax candidates -> predictions (as float).
__global__ void combine_pred(const float* __restrict__ cval,
                             const int* __restrict__ cidx,
                             float* __restrict__ pred) {
    int r = blockIdx.x * 256 + threadIdx.x;
    if (r >= ROWS) return;
    float v = cval[r * 3]; int i = cidx[r * 3];
    if (cval[r * 3 + 1] > v) { v = cval[r * 3 + 1]; i = cidx[r * 3 + 1]; }
    if (cval[r * 3 + 2] > v) { v = cval[r * 3 + 2]; i = cidx[r * 3 + 2]; }
    pred[r] = (float)i;
}

// -------------------------------------------------------------------------
extern "C" void kernel_launch(void* const* d_in, const int* in_sizes, int n_in,
                              void* d_out, int out_size, void* d_ws, size_t ws_size,
                              hipStream_t stream) {
    const float* hiddens = (const float*)d_in[0];
    const float* Wp      = (const float*)d_in[1];
    const float* bp      = (const float*)d_in[2];
    const float* Wv      = (const float*)d_in[3];
    const float* bv      = (const float*)d_in[4];
    const float* src_att = (const float*)d_in[5];
    const float* src_map = (const float*)d_in[6];
    const float* tgt_att = (const float*)d_in[7];
    const float* tgt_map = (const float*)d_in[8];

    float* out  = (float*)d_out;
    float* pred = out + (size_t)ROWS * OUTW;

    // workspace layout (bytes)
    char* ws = (char*)d_ws;
    float* p_ws   = (float*)(ws);                       // 24 KB
    int*   sidx   = (int*)(ws + (24 << 10));            // 8 KB
    int*   tidx   = (int*)(ws + (32 << 10));            // 8 KB
    float* cval   = (float*)(ws + (40 << 10));          // 24 KB
    int*   cidx   = (int*)(ws + (64 << 10));            // 24 KB
    __hip_bfloat16* A_bf = (__hip_bfloat16*)(ws + (128 << 10));              // 2 MB
    __hip_bfloat16* Wt   = (__hip_bfloat16*)(ws + (128 << 10) + (2 << 20));  // 32.75 MB

    // conversions
    convert_a<<<ROWS * Hq / 4 / 256, 256, 0, stream>>>(hiddens, A_bf);
    {
        dim3 tg(Vq / 32, Hq / 32);   // (1000, 16)
        dim3 tb(32, 8);
        transpose_wv<<<tg, tb, 0, stream>>>(Wv, Wt);
    }

    // gate probabilities + one-hot indices
    compute_p<<<ROWS, 64, 0, stream>>>(hiddens, Wp, bp, p_ws);
    extract_idx<<<Bq * Sq, 64, 0, stream>>>(src_map, SDVq, sidx);
    extract_idx<<<Bq * Tq, 64, 0, stream>>>(tgt_map, TDVq, tidx);

    // scores GEMM (MFMA) into vocab region of out
    {
        dim3 gg(ROWS / 128, Vq / 128);   // (16, 250)
        gemm_mfma<<<gg, 256, 0, stream>>>(A_bf, Wt, bv, out);
    }

    // in-place softmax * p_generate, fused vocab argmax
    softmax_rows<<<ROWS, 256, 0, stream>>>(out, p_ws, cval, cidx);

    // copy distributions, fused region argmax
    copy_scatter<<<ROWS, 256, 0, stream>>>(src_att, sidx, p_ws, 0, 1, Sq, SDVq,
                                           out, Vq, cval, cidx);
    copy_scatter<<<ROWS, 256, 0, stream>>>(tgt_att, tidx, p_ws, 1, 2, TDVq, TDVq,
                                           out, Vq + SDVq, cval, cidx);

    // predictions
    combine_pred<<<(ROWS + 255) / 256, 256, 0, stream>>>(cval, cidx, pred);
}